// Round 1
// baseline (633.719 us; speedup 1.0000x reference)
//
#include <hip/hip_runtime.h>
#include <hip/hip_bf16.h>

typedef __bf16 bf16x8 __attribute__((ext_vector_type(8)));
typedef float f32x4 __attribute__((ext_vector_type(4)));
typedef unsigned short u16x8 __attribute__((ext_vector_type(8)));
typedef unsigned short u16x4 __attribute__((ext_vector_type(4)));

#define DEV static __device__ __forceinline__

DEV unsigned short f2bf(float f) {
    unsigned u = __builtin_bit_cast(unsigned, f);
    u += 0x7fffu + ((u >> 16) & 1u);   // round-to-nearest-even
    return (unsigned short)(u >> 16);
}
DEV float bf2f(unsigned short h) {
    unsigned u = ((unsigned)h) << 16;
    return __builtin_bit_cast(float, u);
}

// ---------------------------------------------------------------------------
// Generic GEMM: C[M,N] = A[M,K](bf16,row-major) @ BT[N,K](bf16)^T
// EPI 0: store bf16 C.  EPI 1: store fp32 (res + C).
// BM=BN=128, BK=32, 256 threads = 4 waves, each wave 64x64 (4x4 MFMA frags).
// ---------------------------------------------------------------------------
template <int EPI>
__global__ __launch_bounds__(256)
void gemm_bt(const unsigned short* __restrict__ A,
             const unsigned short* __restrict__ BT,
             unsigned short* __restrict__ outB,
             float* __restrict__ outF,
             const float* __restrict__ res,
             int M, int N, int K)
{
    __shared__ alignas(16) unsigned short As[128][40];   // +8 pad: 80B stride
    __shared__ alignas(16) unsigned short Bs[128][40];

    const int tid  = threadIdx.x;
    const int lane = tid & 63;
    const int wave = tid >> 6;
    const int bm = blockIdx.y * 128;
    const int bn = blockIdx.x * 128;
    const int wm = (wave >> 1) * 64;
    const int wn = (wave & 1) * 64;
    const int lr = lane & 15;
    const int lg = lane >> 4;
    const int srow = tid >> 2;          // 0..63
    const int scol = (tid & 3) * 8;     // 0,8,16,24

    const unsigned short* Aptr0 = A  + (size_t)(bm + srow)      * K + scol;
    const unsigned short* Aptr1 = A  + (size_t)(bm + srow + 64) * K + scol;
    const unsigned short* Bptr0 = BT + (size_t)(bn + srow)      * K + scol;
    const unsigned short* Bptr1 = BT + (size_t)(bn + srow + 64) * K + scol;

    f32x4 acc[4][4] = {};
    u16x8 ra0, ra1, rb0, rb1;

    auto gload = [&](int kt) {
        const size_t o = (size_t)kt * 32;
        ra0 = *reinterpret_cast<const u16x8*>(Aptr0 + o);
        ra1 = *reinterpret_cast<const u16x8*>(Aptr1 + o);
        rb0 = *reinterpret_cast<const u16x8*>(Bptr0 + o);
        rb1 = *reinterpret_cast<const u16x8*>(Bptr1 + o);
    };
    auto lwrite = [&]() {
        *reinterpret_cast<u16x8*>(&As[srow][scol])      = ra0;
        *reinterpret_cast<u16x8*>(&As[srow + 64][scol]) = ra1;
        *reinterpret_cast<u16x8*>(&Bs[srow][scol])      = rb0;
        *reinterpret_cast<u16x8*>(&Bs[srow + 64][scol]) = rb1;
    };

    const int NT = K >> 5;
    gload(0);
    lwrite();
    __syncthreads();

    for (int kt = 0; kt < NT; ++kt) {
        if (kt + 1 < NT) gload(kt + 1);
        bf16x8 af[4], bfr[4];
#pragma unroll
        for (int i = 0; i < 4; ++i) {
            af[i]  = *reinterpret_cast<const bf16x8*>(&As[wm + i * 16 + lr][lg * 8]);
            bfr[i] = *reinterpret_cast<const bf16x8*>(&Bs[wn + i * 16 + lr][lg * 8]);
        }
#pragma unroll
        for (int i = 0; i < 4; ++i)
#pragma unroll
            for (int j = 0; j < 4; ++j)
                acc[i][j] = __builtin_amdgcn_mfma_f32_16x16x32_bf16(af[i], bfr[j], acc[i][j], 0, 0, 0);
        __syncthreads();
        if (kt + 1 < NT) lwrite();
        __syncthreads();
    }

#pragma unroll
    for (int i = 0; i < 4; ++i) {
#pragma unroll
        for (int j = 0; j < 4; ++j) {
            const int col = bn + wn + j * 16 + lr;
#pragma unroll
            for (int r = 0; r < 4; ++r) {
                const int row = bm + wm + i * 16 + lg * 4 + r;
                const float v = acc[i][j][r];
                if constexpr (EPI == 0) {
                    outB[(size_t)row * N + col] = f2bf(v);
                } else {
                    outF[(size_t)row * N + col] = res[(size_t)row * N + col] + v;
                }
            }
        }
    }
}

// ---------------------------------------------------------------------------
// RMSNorm: fp32 in [2048][2048] -> bf16 out, weight fp32. One block per row.
// ---------------------------------------------------------------------------
__global__ __launch_bounds__(256)
void rmsnorm_kernel(const float* __restrict__ x, const float* __restrict__ w,
                    unsigned short* __restrict__ out)
{
    const int row = blockIdx.x;
    const int tid = threadIdx.x;
    const float* xr = x + (size_t)row * 2048;
    const float4 a = *reinterpret_cast<const float4*>(xr + tid * 8);
    const float4 b = *reinterpret_cast<const float4*>(xr + tid * 8 + 4);
    float ss = a.x * a.x + a.y * a.y + a.z * a.z + a.w * a.w
             + b.x * b.x + b.y * b.y + b.z * b.z + b.w * b.w;
#pragma unroll
    for (int off = 32; off; off >>= 1) ss += __shfl_xor(ss, off);
    __shared__ float red[4];
    if ((tid & 63) == 0) red[tid >> 6] = ss;
    __syncthreads();
    const float tot = red[0] + red[1] + red[2] + red[3];
    const float sc = rsqrtf(tot * (1.0f / 2048.0f) + 1e-5f);
    const float4 wa = *reinterpret_cast<const float4*>(w + tid * 8);
    const float4 wb = *reinterpret_cast<const float4*>(w + tid * 8 + 4);
    u16x8 o;
    o[0] = f2bf(a.x * sc * wa.x); o[1] = f2bf(a.y * sc * wa.y);
    o[2] = f2bf(a.z * sc * wa.z); o[3] = f2bf(a.w * sc * wa.w);
    o[4] = f2bf(b.x * sc * wb.x); o[5] = f2bf(b.y * sc * wb.y);
    o[6] = f2bf(b.z * sc * wb.z); o[7] = f2bf(b.w * sc * wb.w);
    *reinterpret_cast<u16x8*>(out + (size_t)row * 2048 + tid * 8) = o;
}

// ---------------------------------------------------------------------------
// RoPE in-place on bf16 [2048][16*128]; cos/sin fp32 [2048][64]
// ---------------------------------------------------------------------------
__global__ __launch_bounds__(256)
void rope_kernel(unsigned short* __restrict__ t, const float* __restrict__ cs,
                 const float* __restrict__ sn)
{
    const int idx = blockIdx.x * 256 + threadIdx.x;   // S*D/8
    const int s   = idx >> 8;
    const int col = (idx & 255) * 8;
    const int i0  = (col & 127) >> 1;
    u16x8 v = *reinterpret_cast<const u16x8*>(t + (size_t)s * 2048 + col);
    const float4 c  = *reinterpret_cast<const float4*>(cs + s * 64 + i0);
    const float4 sv = *reinterpret_cast<const float4*>(sn + s * 64 + i0);
    const float cc[4] = {c.x, c.y, c.z, c.w};
    const float ns[4] = {sv.x, sv.y, sv.z, sv.w};
#pragma unroll
    for (int p = 0; p < 4; ++p) {
        const float re = bf2f(v[2 * p]), im = bf2f(v[2 * p + 1]);
        v[2 * p]     = f2bf(re * cc[p] - im * ns[p]);
        v[2 * p + 1] = f2bf(re * ns[p] + im * cc[p]);
    }
    *reinterpret_cast<u16x8*>(t + (size_t)s * 2048 + col) = v;
}

// ---------------------------------------------------------------------------
// bf16 transpose: out[N][M] = in[M][N]^T, 64x64 LDS tiles
// ---------------------------------------------------------------------------
__global__ __launch_bounds__(256)
void transpose_bf16(const unsigned short* __restrict__ in,
                    unsigned short* __restrict__ out, int M, int N)
{
    __shared__ unsigned short t[64][66];
    const int bm = blockIdx.y * 64, bn = blockIdx.x * 64;
    const int tid = threadIdx.x;
    const int r = tid >> 3, c8 = (tid & 7) * 8;
#pragma unroll
    for (int i = 0; i < 2; ++i) {
        const int row = r + i * 32;
        u16x8 v = *reinterpret_cast<const u16x8*>(in + (size_t)(bm + row) * N + bn + c8);
#pragma unroll
        for (int e = 0; e < 8; ++e) t[row][c8 + e] = v[e];
    }
    __syncthreads();
#pragma unroll
    for (int i = 0; i < 2; ++i) {
        const int orow = r + i * 32;
        u16x8 v;
#pragma unroll
        for (int e = 0; e < 8; ++e) v[e] = t[c8 + e][orow];
        *reinterpret_cast<u16x8*>(out + (size_t)(bn + orow) * M + bm + c8) = v;
    }
}

// ---------------------------------------------------------------------------
// Weight convert + transpose: w[K][N] fp32 -> wT[N][K] bf16, 64x64 tiles
// ---------------------------------------------------------------------------
__global__ __launch_bounds__(256)
void convT_kernel(const float* __restrict__ w, unsigned short* __restrict__ wT,
                  int K, int N)
{
    __shared__ unsigned short t[64][66];
    const int bk = blockIdx.y * 64, bn = blockIdx.x * 64;
    const int tid = threadIdx.x;
    const int r = tid >> 4, c4 = (tid & 15) * 4;
#pragma unroll
    for (int i = 0; i < 4; ++i) {
        const int row = r + i * 16;
        const float4 v = *reinterpret_cast<const float4*>(w + (size_t)(bk + row) * N + bn + c4);
        t[row][c4 + 0] = f2bf(v.x); t[row][c4 + 1] = f2bf(v.y);
        t[row][c4 + 2] = f2bf(v.z); t[row][c4 + 3] = f2bf(v.w);
    }
    __syncthreads();
#pragma unroll
    for (int i = 0; i < 4; ++i) {
        const int n = r + i * 16;
        u16x4 o;
#pragma unroll
        for (int e = 0; e < 4; ++e) o[e] = t[c4 + e][n];
        *reinterpret_cast<u16x4*>(wT + (size_t)(bn + n) * K + bk + c4) = o;
    }
}

// ---------------------------------------------------------------------------
// silu(a) * b elementwise, bf16 (g may alias a)
// ---------------------------------------------------------------------------
__global__ __launch_bounds__(256)
void silu_mul_kernel(const unsigned short* __restrict__ a,
                     const unsigned short* __restrict__ b,
                     unsigned short* __restrict__ g)
{
    const size_t idx = (size_t)(blockIdx.x * 256 + threadIdx.x) * 8;
    const u16x8 va = *reinterpret_cast<const u16x8*>(a + idx);
    const u16x8 vb = *reinterpret_cast<const u16x8*>(b + idx);
    u16x8 o;
#pragma unroll
    for (int e = 0; e < 8; ++e) {
        const float x = bf2f(va[e]);
        const float y = bf2f(vb[e]);
        const float s = x / (1.0f + __expf(-x));
        o[e] = f2bf(s * y);
    }
    *reinterpret_cast<u16x8*>(g + idx) = o;
}

// ---------------------------------------------------------------------------
// Causal flash attention. q,k bf16 [2048][16*128]; vT bf16 [16*128][2048].
// Block = (q-block of 64 rows, head); 4 waves x 16 q-rows each; KV tile 64.
// ---------------------------------------------------------------------------
__global__ __launch_bounds__(256)
void flash_attn(const unsigned short* __restrict__ q,
                const unsigned short* __restrict__ k,
                const unsigned short* __restrict__ vT,
                unsigned short* __restrict__ attn)
{
    __shared__ alignas(16) unsigned short Ks[64][136];   // [kv][hd], pad 8
    __shared__ alignas(16) unsigned short Vs[128][72];   // [hd][kv], pad 8
    __shared__ alignas(16) unsigned short Ps[4][16][72]; // per-wave [q][kv]

    const int hh = blockIdx.y;
    const int qb = blockIdx.x;
    const int tid = threadIdx.x;
    const int lane = tid & 63, wave = tid >> 6;
    const int lr = lane & 15, lg = lane >> 4;
    const int q0 = qb * 64 + wave * 16;

    bf16x8 qf[4];
#pragma unroll
    for (int c = 0; c < 4; ++c)
        qf[c] = *reinterpret_cast<const bf16x8*>(
            q + (size_t)(q0 + lr) * 2048 + hh * 128 + c * 32 + lg * 8);

    f32x4 oacc[8] = {};
    float m_r[4], l_r[4];
#pragma unroll
    for (int r = 0; r < 4; ++r) { m_r[r] = -INFINITY; l_r[r] = 0.0f; }
    const float scale = 0.08838834764831845f;   // 1/sqrt(128)

    for (int kt = 0; kt <= qb; ++kt) {
        const int kv0 = kt * 64;
        // stage K [64][128] and V^T [128][64]
#pragma unroll
        for (int i = 0; i < 4; ++i) {
            const int idx = i * 256 + tid;
            {
                const int row = idx >> 4, ch = (idx & 15) * 8;
                *reinterpret_cast<u16x8*>(&Ks[row][ch]) =
                    *reinterpret_cast<const u16x8*>(k + (size_t)(kv0 + row) * 2048 + hh * 128 + ch);
            }
            {
                const int row = idx >> 3, ch = (idx & 7) * 8;
                *reinterpret_cast<u16x8*>(&Vs[row][ch]) =
                    *reinterpret_cast<const u16x8*>(vT + (size_t)(hh * 128 + row) * 2048 + kv0 + ch);
            }
        }
        __syncthreads();

        // S = Q K^T (4 kv col-tiles x 4 hd chunks)
        f32x4 s[4] = {};
#pragma unroll
        for (int ct = 0; ct < 4; ++ct)
#pragma unroll
            for (int c = 0; c < 4; ++c) {
                const bf16x8 kf = *reinterpret_cast<const bf16x8*>(&Ks[ct * 16 + lr][c * 32 + lg * 8]);
                s[ct] = __builtin_amdgcn_mfma_f32_16x16x32_bf16(qf[c], kf, s[ct], 0, 0, 0);
            }
        // scale + causal mask (only diagonal tile needs it)
#pragma unroll
        for (int ct = 0; ct < 4; ++ct)
#pragma unroll
            for (int r = 0; r < 4; ++r) {
                float v = s[ct][r] * scale;
                if (kt == qb) {
                    const int kvg = kv0 + ct * 16 + lr;
                    const int qg  = q0 + lg * 4 + r;
                    if (kvg > qg) v = -INFINITY;
                }
                s[ct][r] = v;
            }
        // online softmax (row reduce across lane&15 axis)
        float mn[4], alpha[4], rs[4];
#pragma unroll
        for (int r = 0; r < 4; ++r) {
            float v = fmaxf(fmaxf(s[0][r], s[1][r]), fmaxf(s[2][r], s[3][r]));
            v = fmaxf(v, __shfl_xor(v, 1));
            v = fmaxf(v, __shfl_xor(v, 2));
            v = fmaxf(v, __shfl_xor(v, 4));
            v = fmaxf(v, __shfl_xor(v, 8));
            mn[r] = fmaxf(m_r[r], v);
            alpha[r] = __expf(m_r[r] - mn[r]);
            m_r[r] = mn[r];
            rs[r] = 0.0f;
        }
#pragma unroll
        for (int ct = 0; ct < 4; ++ct)
#pragma unroll
            for (int r = 0; r < 4; ++r) {
                const float p = __expf(s[ct][r] - mn[r]);
                s[ct][r] = p;
                rs[r] += p;
            }
#pragma unroll
        for (int r = 0; r < 4; ++r) {
            float t2 = rs[r];
            t2 += __shfl_xor(t2, 1);
            t2 += __shfl_xor(t2, 2);
            t2 += __shfl_xor(t2, 4);
            t2 += __shfl_xor(t2, 8);
            l_r[r] = l_r[r] * alpha[r] + t2;
        }
#pragma unroll
        for (int ot = 0; ot < 8; ++ot)
#pragma unroll
            for (int r = 0; r < 4; ++r) oacc[ot][r] *= alpha[r];

        // P -> per-wave LDS (bf16)
#pragma unroll
        for (int ct = 0; ct < 4; ++ct)
#pragma unroll
            for (int r = 0; r < 4; ++r)
                Ps[wave][lg * 4 + r][ct * 16 + lr] = f2bf(s[ct][r]);

        // O += P V  (A = P from LDS, B = V^T tile)
#pragma unroll
        for (int c2 = 0; c2 < 2; ++c2) {
            const bf16x8 pf = *reinterpret_cast<const bf16x8*>(&Ps[wave][lr][c2 * 32 + lg * 8]);
#pragma unroll
            for (int ot = 0; ot < 8; ++ot) {
                const bf16x8 vf = *reinterpret_cast<const bf16x8*>(&Vs[ot * 16 + lr][c2 * 32 + lg * 8]);
                oacc[ot] = __builtin_amdgcn_mfma_f32_16x16x32_bf16(pf, vf, oacc[ot], 0, 0, 0);
            }
        }
        __syncthreads();
    }

#pragma unroll
    for (int ot = 0; ot < 8; ++ot)
#pragma unroll
        for (int r = 0; r < 4; ++r) {
            const float v = oacc[ot][r] / l_r[r];
            attn[(size_t)(q0 + lg * 4 + r) * 2048 + hh * 128 + ot * 16 + lr] = f2bf(v);
        }
}

// ---------------------------------------------------------------------------
extern "C" void kernel_launch(void* const* d_in, const int* in_sizes, int n_in,
                              void* d_out, int out_size, void* d_ws, size_t ws_size,
                              hipStream_t stream)
{
    const float* x    = (const float*)d_in[0];
    const float* fcos = (const float*)d_in[1];
    const float* fsin = (const float*)d_in[2];
    // d_in[3] = mask (causal, hardcoded)
    const float* wq  = (const float*)d_in[4];
    const float* wk  = (const float*)d_in[5];
    const float* wv  = (const float*)d_in[6];
    const float* wo  = (const float*)d_in[7];
    const float* w1  = (const float*)d_in[8];
    const float* w2  = (const float*)d_in[9];
    const float* w3  = (const float*)d_in[10];
    const float* anw = (const float*)d_in[11];
    const float* fnw = (const float*)d_in[12];
    float* out = (float*)d_out;

    char* ws = (char*)d_ws;
    size_t off = 0;
    auto alloc = [&](size_t bytes) { void* p = ws + off; off += bytes; return p; };
    const size_t SZ_DD = (size_t)2048 * 2048 * 2;   // 8 MiB
    const size_t SZ_DF = (size_t)2048 * 5632 * 2;   // 22 MiB

    unsigned short* wqT = (unsigned short*)alloc(SZ_DD);
    unsigned short* wkT = (unsigned short*)alloc(SZ_DD);
    unsigned short* wvT = (unsigned short*)alloc(SZ_DD);
    unsigned short* woT = (unsigned short*)alloc(SZ_DD);
    unsigned short* w1T = (unsigned short*)alloc(SZ_DF);
    unsigned short* w3T = (unsigned short*)alloc(SZ_DF);
    unsigned short* w2T = (unsigned short*)alloc(SZ_DF);
    char* reg1 = (char*)alloc(3 * SZ_DD);   // xn,q,k  -> later t1
    char* reg2 = (char*)alloc(3 * SZ_DD);   // v,vT,attn -> later t3
    unsigned short* hn = (unsigned short*)alloc(SZ_DD);

    unsigned short* xn  = (unsigned short*)reg1;
    unsigned short* qb  = (unsigned short*)(reg1 + SZ_DD);
    unsigned short* kb  = (unsigned short*)(reg1 + 2 * SZ_DD);
    unsigned short* t1  = (unsigned short*)reg1;
    unsigned short* vb  = (unsigned short*)reg2;
    unsigned short* vTb = (unsigned short*)(reg2 + SZ_DD);
    unsigned short* ab  = (unsigned short*)(reg2 + 2 * SZ_DD);
    unsigned short* t3  = (unsigned short*)reg2;

    // weight fp32 -> bf16 transposed
    convT_kernel<<<dim3(32, 32), 256, 0, stream>>>(wq, wqT, 2048, 2048);
    convT_kernel<<<dim3(32, 32), 256, 0, stream>>>(wk, wkT, 2048, 2048);
    convT_kernel<<<dim3(32, 32), 256, 0, stream>>>(wv, wvT, 2048, 2048);
    convT_kernel<<<dim3(32, 32), 256, 0, stream>>>(wo, woT, 2048, 2048);
    convT_kernel<<<dim3(88, 32), 256, 0, stream>>>(w1, w1T, 2048, 5632);
    convT_kernel<<<dim3(88, 32), 256, 0, stream>>>(w3, w3T, 2048, 5632);
    convT_kernel<<<dim3(32, 88), 256, 0, stream>>>(w2, w2T, 5632, 2048);

    // attention block
    rmsnorm_kernel<<<2048, 256, 0, stream>>>(x, anw, xn);
    gemm_bt<0><<<dim3(16, 16), 256, 0, stream>>>(xn, wqT, qb, nullptr, nullptr, 2048, 2048, 2048);
    gemm_bt<0><<<dim3(16, 16), 256, 0, stream>>>(xn, wkT, kb, nullptr, nullptr, 2048, 2048, 2048);
    gemm_bt<0><<<dim3(16, 16), 256, 0, stream>>>(xn, wvT, vb, nullptr, nullptr, 2048, 2048, 2048);
    rope_kernel<<<2048, 256, 0, stream>>>(qb, fcos, fsin);
    rope_kernel<<<2048, 256, 0, stream>>>(kb, fcos, fsin);
    transpose_bf16<<<dim3(32, 32), 256, 0, stream>>>(vb, vTb, 2048, 2048);
    flash_attn<<<dim3(32, 16), 256, 0, stream>>>(qb, kb, vTb, ab);
    gemm_bt<1><<<dim3(16, 16), 256, 0, stream>>>(ab, woT, nullptr, out, x, 2048, 2048, 2048);

    // FFN block
    rmsnorm_kernel<<<2048, 256, 0, stream>>>(out, fnw, hn);
    gemm_bt<0><<<dim3(44, 16), 256, 0, stream>>>(hn, w1T, t1, nullptr, nullptr, 2048, 5632, 2048);
    gemm_bt<0><<<dim3(44, 16), 256, 0, stream>>>(hn, w3T, t3, nullptr, nullptr, 2048, 5632, 2048);
    silu_mul_kernel<<<5632, 256, 0, stream>>>(t1, t3, t1);
    gemm_bt<1><<<dim3(16, 16), 256, 0, stream>>>(t1, w2T, nullptr, out, out, 2048, 2048, 5632);
}